// Round 6
// baseline (1364.849 us; speedup 1.0000x reference)
//
#include <hip/hip_runtime.h>

// ---------------------------------------------------------------------------
// SRU LM as ONE persistent mega-kernel (256 blocks x 1024 thr, 1 block/CU).
// emb-gather -> SRU(512->1024,k4) -> 4x SRU(1024,k3) -> SRU(1024->512,k4)
//   -> logits = h @ emb^T + bias
// Grid barrier v2: per-block flag slots (64B apart) + leader scan — no
// serialized single-line RMWs (round-5 lesson: 256 atomicAdds on one line
// cost ~33us/sync).
// GEMM v3: persistent cross-tile K-stream — 2 barriers per K-step, frags
// up-front, stage(p+2) overlapped with MFMA, counted vmcnt(4), one
// prologue drain per PHASE (not per tile).
// ---------------------------------------------------------------------------

typedef __attribute__((ext_vector_type(8))) __bf16 bf16x8;
typedef __attribute__((ext_vector_type(4))) float f32x4;
typedef __attribute__((ext_vector_type(4))) float float4v;
typedef __attribute__((ext_vector_type(4))) unsigned short u16x4;

__device__ __forceinline__ unsigned short f2bf(float f) {
  unsigned int u = __builtin_bit_cast(unsigned int, f);
  u += 0x7fffu + ((u >> 16) & 1u);          // RNE
  return (unsigned short)(u >> 16);
}
__device__ __forceinline__ float bf2f(unsigned short v) {
  unsigned int u = ((unsigned int)v) << 16;
  return __builtin_bit_cast(float, u);
}

#define GLDS16(SRC, DST)                                                      \
  __builtin_amdgcn_global_load_lds(                                           \
      (__attribute__((address_space(1))) void*)(SRC),                         \
      (__attribute__((address_space(3))) void*)(DST), 16, 0, 0)

// --------------------------- grid barrier v2 -------------------------------
// slots: 256 x 16 u32 (64B stride).  gen: one u32.  All zeroed per call.
// Release: __syncthreads drains each thread's stores; tid0 __threadfence
// (agent: wbl2) publishes the XCD L2; slot store release.  Leader (block 0)
// polls slots in parallel (thread i polls slot i), fences (inv), bumps gen.
// Waiters poll gen then fence (inv).
__device__ __forceinline__ void grid_sync(unsigned* slots, unsigned* gen,
                                          unsigned target, int bid, int tid) {
  __syncthreads();
  if (bid == 0) {
    if (tid == 0) __threadfence();
    __syncthreads();
    if (tid >= 1 && tid < 256) {
      while (__hip_atomic_load(&slots[tid << 4], __ATOMIC_RELAXED,
                               __HIP_MEMORY_SCOPE_AGENT) < target)
        __builtin_amdgcn_s_sleep(1);
    }
    __syncthreads();
    if (tid == 0) {
      __threadfence();
      __hip_atomic_store(gen, target, __ATOMIC_RELEASE,
                         __HIP_MEMORY_SCOPE_AGENT);
    }
  } else if (tid == 0) {
    __threadfence();
    __hip_atomic_store(&slots[bid << 4], target, __ATOMIC_RELEASE,
                       __HIP_MEMORY_SCOPE_AGENT);
    while (__hip_atomic_load(gen, __ATOMIC_RELAXED,
                             __HIP_MEMORY_SCOPE_AGENT) < target)
      __builtin_amdgcn_s_sleep(1);
    __threadfence();
  }
  __syncthreads();
}

// --------------------------- GEMM v3: K-stream -----------------------------
// C[m][n] = sum_k A[m][k]*B[n][k] (+bias).  A:(M,K) bf16, B:(N,K) bf16,
// C:(M,N) fp32.  Block's tiles: t = bid, bid+256, ... (< total).  The whole
// per-block work is one stream of P = ntiles*NT K-tiles, double-buffered in
// LDS; per K-step: {ds_read 16 frags; lgkmcnt(0); barrier; stage(p+2);
// 32 MFMA; [C-write at tile end]; vmcnt(4); barrier}.
// colmajor (logits): m0=(t&15)*256 const per block -> A-panel L2 locality.
__device__ __forceinline__ void gemm_stream(
    const unsigned short* __restrict__ A, const unsigned short* __restrict__ B,
    float* __restrict__ C, const float* __restrict__ bias, int N, int K,
    int total, int tiles_n, bool colmajor, unsigned short* __restrict__ sm,
    int bid, int tid) {
  const int lane = tid & 63, w = tid >> 6;
  const int wm = w >> 2, wn = w & 3;           // 4x4 wave grid, 64x64/wave
  const int srow = lane >> 3, sslot = (lane & 7) ^ srow;
  const int fr = lane & 15, lg = lane >> 4;
  const int NT = K >> 6;                       // 8 or 16 (power of 2)
  const int ktsh = (NT == 8) ? 3 : 4;
  const int ntb = (bid < total) ? ((total - bid + 255) >> 8) : 0;
  if (ntb == 0) return;
  const int P = ntb << ktsh;

#define STAGE_P(p)                                                            \
  {                                                                           \
    const int i_ = (p) >> ktsh, kt_ = (p) & (NT - 1);                         \
    const int t_ = bid + (i_ << 8);                                           \
    int m0_, n0_;                                                             \
    if (colmajor) { m0_ = (t_ & 15) << 8; n0_ = (t_ >> 4) << 8; }             \
    else { m0_ = (t_ / tiles_n) << 8; n0_ = (t_ % tiles_n) << 8; }            \
    unsigned short* dA_ = sm + ((p) & 1) * 32768;                             \
    unsigned short* dB_ = dA_ + 16384;                                        \
    const int k0_ = kt_ << 6;                                                 \
    _Pragma("unroll") for (int j = 0; j < 2; ++j) {                           \
      const unsigned short* sa_ =                                             \
          A + (size_t)(m0_ + j * 128 + w * 8 + srow) * K + k0_ + sslot * 8;   \
      GLDS16(sa_, dA_ + j * 8192 + w * 512);                                  \
    }                                                                         \
    _Pragma("unroll") for (int j = 0; j < 2; ++j) {                           \
      const unsigned short* sb_ =                                             \
          B + (size_t)(n0_ + j * 128 + w * 8 + srow) * K + k0_ + sslot * 8;   \
      GLDS16(sb_, dB_ + j * 8192 + w * 512);                                  \
    }                                                                         \
  }

  f32x4 acc[4][4] = {};
  STAGE_P(0);
  STAGE_P(1);                                  // P >= NT >= 8 always
  asm volatile("s_waitcnt vmcnt(4)" ::: "memory");   // K-tile 0 landed
  __builtin_amdgcn_s_barrier();

  for (int p = 0; p < P; ++p) {
    const unsigned short* As = sm + (p & 1) * 32768;
    const unsigned short* Bs = As + 16384;
    bf16x8 afr[2][4], bfr[2][4];
#pragma unroll
    for (int kk = 0; kk < 2; ++kk) {
#pragma unroll
      for (int q = 0; q < 4; ++q) {
        const int row = wm * 64 + q * 16 + fr;
        const int slot = (kk * 4 + lg) ^ (row & 7);
        afr[kk][q] = *(const bf16x8*)&As[row * 64 + slot * 8];
      }
#pragma unroll
      for (int n = 0; n < 4; ++n) {
        const int row = wn * 64 + n * 16 + fr;
        const int slot = (kk * 4 + lg) ^ (row & 7);
        bfr[kk][n] = *(const bf16x8*)&Bs[row * 64 + slot * 8];
      }
    }
    asm volatile("s_waitcnt lgkmcnt(0)" ::: "memory");
    __builtin_amdgcn_sched_barrier(0);
    __builtin_amdgcn_s_barrier();              // all waves done with buf[p&1]
    if (p + 2 < P) STAGE_P(p + 2);             // overwrite freed buffer
    __builtin_amdgcn_s_setprio(1);
#pragma unroll
    for (int kk = 0; kk < 2; ++kk)
#pragma unroll
      for (int q = 0; q < 4; ++q)
#pragma unroll
        for (int n = 0; n < 4; ++n)
          acc[q][n] = __builtin_amdgcn_mfma_f32_16x16x32_bf16(
              afr[kk][q], bfr[kk][n], acc[q][n], 0, 0, 0);
    __builtin_amdgcn_s_setprio(0);
    if ((p & (NT - 1)) == NT - 1) {            // tile finished: C-write
      const int t_ = bid + ((p >> ktsh) << 8);
      int m0, n0;
      if (colmajor) { m0 = (t_ & 15) << 8; n0 = (t_ >> 4) << 8; }
      else { m0 = (t_ / tiles_n) << 8; n0 = (t_ % tiles_n) << 8; }
#pragma unroll
      for (int n = 0; n < 4; ++n) {
        const int col = n0 + wn * 64 + n * 16 + fr;
        const float bv = bias ? bias[col] : 0.0f;
#pragma unroll
        for (int m = 0; m < 4; ++m) {
          const int row = m0 + wm * 64 + m * 16 + lg * 4;
#pragma unroll
          for (int r = 0; r < 4; ++r)
            C[(size_t)(row + r) * N + col] = acc[m][n][r] + bv;
        }
      }
#pragma unroll
      for (int q = 0; q < 4; ++q)
#pragma unroll
        for (int n = 0; n < 4; ++n)
          acc[q][n] = f32x4{0.f, 0.f, 0.f, 0.f};
    }
    if (p + 2 < P)
      asm volatile("s_waitcnt vmcnt(4)" ::: "memory");  // K-tile p+1 landed
    else
      asm volatile("s_waitcnt vmcnt(0)" ::: "memory");
    __builtin_amdgcn_s_barrier();
  }
#undef STAGE_P
}

// --------------------------- scan phase ------------------------------------
// 4-deep software-pipelined SRU scan; waves spread across blocks.
template <bool K4, int NOUT>
__device__ __forceinline__ void scan_phase(
    const float* __restrict__ U, const float* __restrict__ bias,
    const float* __restrict__ c0, const unsigned short* __restrict__ hin,
    unsigned short* __restrict__ hout, int bid, int tid) {
  const int nwave = (NOUT * 32) >> 6;
  const int q = (nwave + 255) >> 8;
  const int wv = tid >> 6;
  if (wv >= q) return;
  const int g = bid * q + wv;
  if (g >= nwave) return;
  const int idx = g * 64 + (tid & 63);

  const int b = idx / NOUT;
  const int d = idx - b * NOUT;
  const float biasf = bias[d];
  const float biasr = bias[NOUT + d];
  float c = c0[idx];
  const int rowlen = (K4 ? 4 : 3) * NOUT;
  const float* Up = U + (size_t)b * rowlen + d;
  const size_t lstride = (size_t)32 * rowlen;
  const unsigned short* hp = hin + (size_t)b * NOUT + d;
  unsigned short* op = hout + (size_t)b * NOUT + d;
  const size_t hstride = (size_t)32 * NOUT;

  float xt0, fr0, rr0, hw0, xt1, fr1, rr1, hw1;
  float xt2, fr2, rr2, hw2, xt3, fr3, rr3, hw3;

#define SRU_LOAD(S)                                                           \
  do {                                                                        \
    xt##S = Up[0];                                                            \
    fr##S = Up[NOUT];                                                         \
    rr##S = Up[2 * NOUT];                                                     \
    hw##S = K4 ? Up[3 * NOUT] : bf2f(*hp);                                    \
    Up += lstride;                                                            \
    hp += hstride;                                                            \
  } while (0)

#define SRU_STEP(S)                                                           \
  do {                                                                        \
    const float f = 1.0f / (1.0f + __expf(-(fr##S + biasf)));                 \
    const float r = 1.0f / (1.0f + __expf(-(rr##S + biasr)));                 \
    c = f * c + (1.0f - f) * xt##S;                                           \
    const float e2 = __expf(2.0f * c);                                        \
    const float g2 = 1.0f - 2.0f / (e2 + 1.0f);                               \
    *op = f2bf(r * g2 + (1.0f - r) * hw##S);                                  \
    op += hstride;                                                            \
  } while (0)

  SRU_LOAD(0); SRU_LOAD(1); SRU_LOAD(2); SRU_LOAD(3);
  for (int l = 0; l < 124; l += 4) {
    SRU_STEP(0); SRU_LOAD(0);
    SRU_STEP(1); SRU_LOAD(1);
    SRU_STEP(2); SRU_LOAD(2);
    SRU_STEP(3); SRU_LOAD(3);
  }
  SRU_STEP(0); SRU_STEP(1); SRU_STEP(2); SRU_STEP(3);
#undef SRU_LOAD
#undef SRU_STEP
}

// --------------------------- mega kernel -----------------------------------
__global__ __launch_bounds__(1024, 4)
void mega(const int* __restrict__ x, const float* __restrict__ c1,
          const float* __restrict__ c2, const float* __restrict__ c3,
          const float* __restrict__ emb, const float* __restrict__ obias,
          const float* __restrict__ W1, const float* __restrict__ b1,
          const float* __restrict__ W2, const float* __restrict__ b2,
          const float* __restrict__ W3, const float* __restrict__ b3,
          unsigned short* __restrict__ embbf, unsigned short* __restrict__ hbfA,
          unsigned short* __restrict__ hbfB, unsigned short* __restrict__ W1t,
          unsigned short* __restrict__ W2t, unsigned short* __restrict__ W3t,
          float* __restrict__ U, float* __restrict__ out,
          unsigned* slots, unsigned* gen) {
  __shared__ __align__(16) unsigned char smem[131072];
  unsigned short* sm16 = (unsigned short*)smem;
  const int bid = blockIdx.x;
  const int tid = threadIdx.x;
  const int gtid = bid * 1024 + tid;
  unsigned bt = 0;

  // ---------------- phase 0: prep (cvt, gather, transposes) ----------------
  for (int i = gtid; i < 4096000; i += 262144) {       // emb f32 -> bf16, x4
    const float4v v = ((const float4v*)emb)[i];
    u16x4 o;
    o.x = f2bf(v.x); o.y = f2bf(v.y); o.z = f2bf(v.z); o.w = f2bf(v.w);
    ((u16x4*)embbf)[i] = o;
  }
  for (int i = gtid; i < 2097152; i += 262144) {       // token gather
    const int row = i >> 9, e = i & 511;
    const int tok = x[row];
    hbfA[i] = f2bf(emb[((size_t)tok << 9) + e]);
  }
  {                                                    // 16384 32x32 transposes
    const int grp = tid >> 8;                          // 4 tiles per block/iter
    const int t2 = tid & 255;
    const int tx = t2 & 31, ty = t2 >> 5;
    float* tile = (float*)(smem + grp * 4352);         // 32x33 f32 = 4224 B
    for (int it = 0; it < 16; ++it) {
      const int tg = (it * 256 + bid) * 4 + grp;       // 0..16383
      const float* W; unsigned short* Wt; int K, N, bx, by;
      if (tg < 2048)       { W = W1; Wt = W1t; K = 512;  N = 4096;
                             bx = tg & 127; by = tg >> 7; }
      else if (tg < 14336) { const int r = tg - 2048; const int i2 = r / 3072;
                             const int rr = r - i2 * 3072;
                             W = W2 + (size_t)i2 * 3145728;
                             Wt = W2t + (size_t)i2 * 3145728;
                             K = 1024; N = 3072; bx = rr % 96; by = rr / 96; }
      else                 { const int r = tg - 14336; W = W3; Wt = W3t;
                             K = 1024; N = 2048; bx = r & 63; by = r >> 6; }
      const int n0 = bx * 32, k0 = by * 32;
#pragma unroll
      for (int i2 = 0; i2 < 32; i2 += 8)
        tile[(ty + i2) * 33 + tx] = W[(size_t)(k0 + ty + i2) * N + n0 + tx];
      __syncthreads();
#pragma unroll
      for (int i2 = 0; i2 < 32; i2 += 8)
        Wt[(size_t)(n0 + ty + i2) * K + k0 + tx] = f2bf(tile[tx * 33 + ty + i2]);
      __syncthreads();
    }
  }
  grid_sync(slots, gen, ++bt, bid, tid);

  // ---------------- layer 1: (512 -> 1024, k=4) ----------------------------
  gemm_stream(hbfA, W1t, U, nullptr, 4096, 512, 256, 16, false, sm16, bid, tid);
  grid_sync(slots, gen, ++bt, bid, tid);
  scan_phase<true, 1024>(U, b1, c1, hbfB, hbfB, bid, tid);
  grid_sync(slots, gen, ++bt, bid, tid);

  // ---------------- mid layers: 4x (1024 -> 1024, k=3) ---------------------
  const unsigned short* hin = hbfB;
  unsigned short* hout = hbfA;
  for (int i = 0; i < 4; ++i) {
    gemm_stream(hin, W2t + (size_t)i * 3145728, U, nullptr, 3072, 1024, 192, 12,
                false, sm16, bid, tid);
    grid_sync(slots, gen, ++bt, bid, tid);
    scan_phase<false, 1024>(U, b2 + i * 2048, c2 + (size_t)i * 32768, hin, hout,
                            bid, tid);
    grid_sync(slots, gen, ++bt, bid, tid);
    const unsigned short* tswap = hin; hin = hout; hout = (unsigned short*)tswap;
  }

  // ---------------- final SRU: (1024 -> 512, k=4) --------------------------
  gemm_stream(hin, W3t, U, nullptr, 2048, 1024, 128, 8, false, sm16, bid, tid);
  grid_sync(slots, gen, ++bt, bid, tid);
  scan_phase<true, 512>(U, b3, c3, hout, hout, bid, tid);   // writes hout
  grid_sync(slots, gen, ++bt, bid, tid);

  // ---------------- logits: (4096 x 32000) ---------------------------------
  gemm_stream(hout, embbf, out, obias, 32000, 512, 2000, 125, true, sm16, bid,
              tid);
}

extern "C" void kernel_launch(void* const* d_in, const int* in_sizes, int n_in,
                              void* d_out, int out_size, void* d_ws, size_t ws_size,
                              hipStream_t stream) {
  (void)in_sizes; (void)n_in; (void)out_size; (void)ws_size;
  const int*   x     = (const int*)d_in[0];
  const float* c1    = (const float*)d_in[1];
  const float* c2    = (const float*)d_in[2];
  const float* c3    = (const float*)d_in[3];
  const float* emb   = (const float*)d_in[4];
  const float* obias = (const float*)d_in[5];
  const float* W1    = (const float*)d_in[6];
  const float* b1    = (const float*)d_in[7];
  const float* W2    = (const float*)d_in[8];
  const float* b2    = (const float*)d_in[9];
  const float* W3    = (const float*)d_in[10];
  const float* b3    = (const float*)d_in[11];

  char* ws = (char*)d_ws;
  unsigned short* hbfA  = (unsigned short*)ws;                  //  8,388,608 B
  unsigned short* hbfB  = (unsigned short*)(ws + 8388608);      //  8,388,608 B
  unsigned short* embbf = (unsigned short*)(ws + 16777216);     // 32,768,000 B
  unsigned short* W1t   = (unsigned short*)(ws + 49545216);     //  4,194,304 B
  unsigned short* W2t   = (unsigned short*)(ws + 53739520);     // 25,165,824 B
  unsigned short* W3t   = (unsigned short*)(ws + 78905344);     //  4,194,304 B
  unsigned* bar = (unsigned*)(ws + 104857600);   // 256 slots x 64B, then gen
  float* U = (float*)d_out;   // 64 MB scratch; overwritten by logits at end.

  hipMemsetAsync(bar, 0, 16448, stream);         // slots + gen = 0
  mega<<<256, 1024, 0, stream>>>(x, c1, c2, c3, emb, obias, W1, b1, W2, b2,
                                 W3, b3, embbf, hbfA, hbfB, W1t, W2t, W3t,
                                 U, (float*)d_out, bar, (unsigned*)(ws + 104857600 + 16384));
}

// Round 7
// 1072.446 us; speedup vs baseline: 1.2726x; 1.2726x over previous
//
#include <hip/hip_runtime.h>

// ---------------------------------------------------------------------------
// SRU LM: emb-gather -> SRU(512->1024,k4) -> 4x SRU(1024,k3) -> SRU(1024->512,k4)
//         -> logits = h @ emb^T + bias
// L=128 B=32 E=512 D=1024 V=32000 MID=4
// Round 7: multi-kernel (launch-based sync — megakernel spin barriers cost
// 30-50us/sync, rounds 5-6) + K-STREAM GEMM: each block loops its tiles as
// one continuous stream of K-steps, 2 barriers per 32-MFMA K-step, counted
// vmcnt(4) throughout, ONE prologue drain per stream (not per tile), C-write
// overlapped with in-flight stages.  Scans: 4-deep pipelined.  Prep fused.
// U scratch lives in d_out (overwritten at the end by the logits GEMM).
// ---------------------------------------------------------------------------

typedef __attribute__((ext_vector_type(8))) __bf16 bf16x8;
typedef __attribute__((ext_vector_type(4))) float f32x4;
typedef __attribute__((ext_vector_type(4))) float float4v;
typedef __attribute__((ext_vector_type(4))) unsigned short u16x4;

__device__ __forceinline__ unsigned short f2bf(float f) {
  unsigned int u = __builtin_bit_cast(unsigned int, f);
  u += 0x7fffu + ((u >> 16) & 1u);          // RNE
  return (unsigned short)(u >> 16);
}
__device__ __forceinline__ float bf2f(unsigned short v) {
  unsigned int u = ((unsigned int)v) << 16;
  return __builtin_bit_cast(float, u);
}

#define GLDS16(SRC, DST)                                                      \
  __builtin_amdgcn_global_load_lds(                                           \
      (__attribute__((address_space(1))) void*)(SRC),                         \
      (__attribute__((address_space(3))) void*)(DST), 16, 0, 0)

// ---------------------------------------------------------------------------
// K-stream GEMM.  C[m][n] = sum_k A[m][k]*B[n][k] (+bias[n]).
// A:(M,K) bf16, B:(N,K) bf16, C:(M,N) fp32.  M%256==0, N%256==0, K=512|1024.
// Grid = 256 x 1024 thr (16 waves, 4x4 grid, 64x64 out/wave, 1 block/CU).
// Block bid owns tiles t = bid, bid+256, ... (< total); its whole work is a
// stream of P = ntiles*NT K-steps, LDS double-buffered:
//   per step: {ds_read 16 frags; lgkmcnt(0); barrier; stage(p+2); 32 MFMA;
//              [C-write at tile end]; vmcnt(4); barrier}
// colmajor (logits): m0 = (t&15)*256 is constant per block -> A-panel L2
// locality; B panels distinct across blocks.
// ---------------------------------------------------------------------------
__global__ __launch_bounds__(1024, 4)
void gemm_stream_k(const unsigned short* __restrict__ A,
                   const unsigned short* __restrict__ B,
                   float* __restrict__ C, const float* __restrict__ bias,
                   int N, int K, int total, int tiles_n, int colmajor) {
  __shared__ __align__(16) unsigned short sm[2][2][16384];  // [buf][A/B][256*64]

  const int bid = blockIdx.x, tid = threadIdx.x;
  const int lane = tid & 63, w = tid >> 6;
  const int wm = w >> 2, wn = w & 3;           // 4x4 wave grid, 64x64/wave
  const int srow = lane >> 3, sslot = (lane & 7) ^ srow;
  const int fr = lane & 15, lg = lane >> 4;
  const int NT = K >> 6;                       // 8 or 16 (power of 2)
  const int ktsh = (NT == 8) ? 3 : 4;
  if (bid >= total) return;
  const int ntb = (total - bid + 255) >> 8;
  const int P = ntb << ktsh;

#define STAGE_P(p)                                                            \
  {                                                                           \
    const int i_ = (p) >> ktsh, kt_ = (p) & (NT - 1);                         \
    const int t_ = bid + (i_ << 8);                                           \
    int m0_, n0_;                                                             \
    if (colmajor) { m0_ = (t_ & 15) << 8; n0_ = (t_ >> 4) << 8; }             \
    else { m0_ = (t_ / tiles_n) << 8; n0_ = (t_ % tiles_n) << 8; }            \
    unsigned short* dA_ = &sm[(p) & 1][0][0];                                 \
    unsigned short* dB_ = &sm[(p) & 1][1][0];                                 \
    const int k0_ = kt_ << 6;                                                 \
    _Pragma("unroll") for (int j = 0; j < 2; ++j) {                           \
      const unsigned short* sa_ =                                             \
          A + (size_t)(m0_ + j * 128 + w * 8 + srow) * K + k0_ + sslot * 8;   \
      GLDS16(sa_, dA_ + j * 8192 + w * 512);                                  \
    }                                                                         \
    _Pragma("unroll") for (int j = 0; j < 2; ++j) {                           \
      const unsigned short* sb_ =                                             \
          B + (size_t)(n0_ + j * 128 + w * 8 + srow) * K + k0_ + sslot * 8;   \
      GLDS16(sb_, dB_ + j * 8192 + w * 512);                                  \
    }                                                                         \
  }

  f32x4 acc[4][4] = {};
  STAGE_P(0);
  STAGE_P(1);                                  // P >= NT >= 8 always
  asm volatile("s_waitcnt vmcnt(4)" ::: "memory");   // K-step 0 landed
  __builtin_amdgcn_s_barrier();

  for (int p = 0; p < P; ++p) {
    const unsigned short* As = &sm[p & 1][0][0];
    const unsigned short* Bs = &sm[p & 1][1][0];
    bf16x8 afr[2][4], bfr[2][4];
#pragma unroll
    for (int kk = 0; kk < 2; ++kk) {
#pragma unroll
      for (int q = 0; q < 4; ++q) {
        const int row = wm * 64 + q * 16 + fr;
        const int slot = (kk * 4 + lg) ^ (row & 7);
        afr[kk][q] = *(const bf16x8*)&As[row * 64 + slot * 8];
      }
#pragma unroll
      for (int n = 0; n < 4; ++n) {
        const int row = wn * 64 + n * 16 + fr;
        const int slot = (kk * 4 + lg) ^ (row & 7);
        bfr[kk][n] = *(const bf16x8*)&Bs[row * 64 + slot * 8];
      }
    }
    asm volatile("s_waitcnt lgkmcnt(0)" ::: "memory");
    __builtin_amdgcn_sched_barrier(0);
    __builtin_amdgcn_s_barrier();              // all waves done with buf[p&1]
    if (p + 2 < P) STAGE_P(p + 2);             // refill freed buffer
    __builtin_amdgcn_s_setprio(1);
#pragma unroll
    for (int kk = 0; kk < 2; ++kk)
#pragma unroll
      for (int q = 0; q < 4; ++q)
#pragma unroll
        for (int n = 0; n < 4; ++n)
          acc[q][n] = __builtin_amdgcn_mfma_f32_16x16x32_bf16(
              afr[kk][q], bfr[kk][n], acc[q][n], 0, 0, 0);
    __builtin_amdgcn_s_setprio(0);
    if ((p & (NT - 1)) == NT - 1) {            // tile finished: C-write
      const int t_ = bid + ((p >> ktsh) << 8);
      int m0, n0;
      if (colmajor) { m0 = (t_ & 15) << 8; n0 = (t_ >> 4) << 8; }
      else { m0 = (t_ / tiles_n) << 8; n0 = (t_ % tiles_n) << 8; }
#pragma unroll
      for (int n = 0; n < 4; ++n) {
        const int col = n0 + wn * 64 + n * 16 + fr;
        const float bv = bias ? bias[col] : 0.0f;
#pragma unroll
        for (int m = 0; m < 4; ++m) {
          const int row = m0 + wm * 64 + m * 16 + lg * 4;
#pragma unroll
          for (int r = 0; r < 4; ++r)
            C[(size_t)(row + r) * N + col] = acc[m][n][r] + bv;
        }
      }
#pragma unroll
      for (int q = 0; q < 4; ++q)
#pragma unroll
        for (int n = 0; n < 4; ++n)
          acc[q][n] = f32x4{0.f, 0.f, 0.f, 0.f};
    }
    if (p + 2 < P)
      asm volatile("s_waitcnt vmcnt(4)" ::: "memory");  // K-step p+1 landed
    else
      asm volatile("s_waitcnt vmcnt(0)" ::: "memory");
    __builtin_amdgcn_s_barrier();
  }
#undef STAGE_P
}

// ---------------------------------------------------------------------------
// SRU scan, 4-deep software-pipelined.  One thread per (b,d) chain, L=128.
// ---------------------------------------------------------------------------
template <bool K4>
__global__ void scan_k(const float* __restrict__ U, const float* __restrict__ bias,
                       const float* __restrict__ c0,
                       const unsigned short* __restrict__ hin,
                       unsigned short* __restrict__ hout, int n_out) {
  const int idx = blockIdx.x * 64 + threadIdx.x;     // 0 .. 32*n_out
  const int b = idx / n_out;
  const int d = idx - b * n_out;
  const float biasf = bias[d];
  const float biasr = bias[n_out + d];
  float c = c0[idx];
  const int rowlen = (K4 ? 4 : 3) * n_out;
  const float* Up = U + (size_t)b * rowlen + d;
  const size_t lstride = (size_t)32 * rowlen;
  const unsigned short* hp = hin + (size_t)b * n_out + d;
  unsigned short* op = hout + (size_t)b * n_out + d;
  const size_t hstride = (size_t)32 * n_out;

  float xt0, fr0, rr0, hw0, xt1, fr1, rr1, hw1;
  float xt2, fr2, rr2, hw2, xt3, fr3, rr3, hw3;

#define SRU_LOAD(S)                                                           \
  do {                                                                        \
    xt##S = Up[0];                                                            \
    fr##S = Up[n_out];                                                        \
    rr##S = Up[2 * n_out];                                                    \
    hw##S = K4 ? Up[3 * n_out] : bf2f(*hp);                                   \
    Up += lstride;                                                            \
    hp += hstride;                                                            \
  } while (0)

#define SRU_STEP(S)                                                           \
  do {                                                                        \
    const float f = 1.0f / (1.0f + __expf(-(fr##S + biasf)));                 \
    const float r = 1.0f / (1.0f + __expf(-(rr##S + biasr)));                 \
    c = f * c + (1.0f - f) * xt##S;                                           \
    const float e2 = __expf(2.0f * c);                                        \
    const float g = 1.0f - 2.0f / (e2 + 1.0f);                                \
    *op = f2bf(r * g + (1.0f - r) * hw##S);                                   \
    op += hstride;                                                            \
  } while (0)

  SRU_LOAD(0); SRU_LOAD(1); SRU_LOAD(2); SRU_LOAD(3);   // l = 0..3
  for (int l = 0; l < 124; l += 4) {                    // l = 0,4,...,120
    SRU_STEP(0); SRU_LOAD(0);                           // load l+4
    SRU_STEP(1); SRU_LOAD(1);
    SRU_STEP(2); SRU_LOAD(2);
    SRU_STEP(3); SRU_LOAD(3);
  }
  SRU_STEP(0); SRU_STEP(1); SRU_STEP(2); SRU_STEP(3);   // l = 124..127
#undef SRU_LOAD
#undef SRU_STEP
}

// ---------------------------------------------------------------------------
// Fused prep: emb->bf16 cvt, token gather, all 6 weight transposes.
// ---------------------------------------------------------------------------
__device__ __forceinline__ void transpose_tile(const float* __restrict__ W,
                                               unsigned short* __restrict__ Wt,
                                               int K, int N, int bx, int by,
                                               int tid) {
  __shared__ float tile[32][33];
  const int n0 = bx * 32, k0 = by * 32;
  const int tx = tid & 31, ty = tid >> 5;   // (32,8)
#pragma unroll
  for (int i = 0; i < 32; i += 8)
    tile[ty + i][tx] = W[(size_t)(k0 + ty + i) * N + n0 + tx];
  __syncthreads();
#pragma unroll
  for (int i = 0; i < 32; i += 8)
    Wt[(size_t)(n0 + ty + i) * K + k0 + tx] = f2bf(tile[tx][ty + i]);
}

__global__ void prep_k(const int* __restrict__ x, const float* __restrict__ emb,
                       const float* __restrict__ W1, const float* __restrict__ W2,
                       const float* __restrict__ W3,
                       unsigned short* __restrict__ embbf,
                       unsigned short* __restrict__ h0,
                       unsigned short* __restrict__ W1t,
                       unsigned short* __restrict__ W2t,
                       unsigned short* __restrict__ W3t) {
  const int blk = blockIdx.x;
  const int tid = threadIdx.x;
  if (blk < 16000) {                                   // cvt emb -> bf16
    const int i = blk * 256 + tid;
    const float4v v = ((const float4v*)emb)[i];
    u16x4 o;
    o.x = f2bf(v.x); o.y = f2bf(v.y); o.z = f2bf(v.z); o.w = f2bf(v.w);
    ((u16x4*)embbf)[i] = o;
  } else if (blk < 24192) {                            // embed gather
    const int i = (blk - 16000) * 256 + tid;           // 0..2097151
    const int row = i >> 9, e = i & 511;
    const int tok = x[row];
    h0[i] = f2bf(emb[((size_t)tok << 9) + e]);
  } else if (blk < 26240) {                            // W1: K=512 N=4096
    const int r = blk - 24192;                         // 128 x 16
    transpose_tile(W1, W1t, 512, 4096, r & 127, r >> 7, tid);
  } else if (blk < 38528) {                            // W2[i]: K=1024 N=3072
    const int r = (blk - 26240);
    const int i = r / 3072, rr = r - i * 3072;         // 96 x 32
    transpose_tile(W2 + (size_t)i * 3145728, W2t + (size_t)i * 3145728,
                   1024, 3072, rr % 96, rr / 96, tid);
  } else {                                             // W3: K=1024 N=2048
    const int r = blk - 38528;                         // 64 x 32
    transpose_tile(W3, W3t, 1024, 2048, r & 63, r >> 6, tid);
  }
}

extern "C" void kernel_launch(void* const* d_in, const int* in_sizes, int n_in,
                              void* d_out, int out_size, void* d_ws, size_t ws_size,
                              hipStream_t stream) {
  (void)in_sizes; (void)n_in; (void)out_size; (void)ws_size;
  const int*   x     = (const int*)d_in[0];
  const float* c1    = (const float*)d_in[1];
  const float* c2    = (const float*)d_in[2];
  const float* c3    = (const float*)d_in[3];
  const float* emb   = (const float*)d_in[4];
  const float* obias = (const float*)d_in[5];
  const float* W1    = (const float*)d_in[6];
  const float* b1    = (const float*)d_in[7];
  const float* W2    = (const float*)d_in[8];
  const float* b2    = (const float*)d_in[9];
  const float* W3    = (const float*)d_in[10];
  const float* b3    = (const float*)d_in[11];

  char* ws = (char*)d_ws;
  unsigned short* hbfA  = (unsigned short*)ws;                  //  8,388,608 B
  unsigned short* hbfB  = (unsigned short*)(ws + 8388608);      //  8,388,608 B
  unsigned short* embbf = (unsigned short*)(ws + 16777216);     // 32,768,000 B
  unsigned short* W1t   = (unsigned short*)(ws + 49545216);     //  4,194,304 B
  unsigned short* W2t   = (unsigned short*)(ws + 53739520);     // 25,165,824 B
  unsigned short* W3t   = (unsigned short*)(ws + 78905344);     //  4,194,304 B
  float* U = (float*)d_out;   // up to 4096*4096 fp32 = 67 MB scratch; d_out is
                              // fully overwritten by the final logits GEMM.

  // all input prep in one launch (cvt, gather, 6 transposes — independent)
  prep_k<<<40576, 256, 0, stream>>>(x, emb, W1, W2, W3, embbf, hbfA,
                                    W1t, W2t, W3t);

  // ---- layer 1: (512 -> 1024, k=4): M=4096 N=4096 K=512, 256 tiles ----
  gemm_stream_k<<<256, 1024, 0, stream>>>(hbfA, W1t, U, nullptr,
                                          4096, 512, 256, 16, 0);
  scan_k<true><<<512, 64, 0, stream>>>(U, b1, c1, hbfB, hbfB, 1024);

  // ---- mid layers: 4x (1024 -> 1024, k=3): M=4096 N=3072 K=1024 ----
  const unsigned short* hin = hbfB;
  unsigned short* hout = hbfA;
  for (int i = 0; i < 4; ++i) {
    gemm_stream_k<<<256, 1024, 0, stream>>>(hin, W2t + (size_t)i * 3145728, U,
                                            nullptr, 3072, 1024, 192, 12, 0);
    scan_k<false><<<512, 64, 0, stream>>>(U, b2 + i * 2048, c2 + (size_t)i * 32768,
                                          hin, hout, 1024);
    const unsigned short* t = hin; hin = hout; hout = (unsigned short*)t;
  }

  // ---- final SRU: (1024 -> 512, k=4): M=4096 N=2048 K=1024, 128 tiles ----
  gemm_stream_k<<<256, 1024, 0, stream>>>(hin, W3t, U, nullptr,
                                          2048, 1024, 128, 8, 0);
  scan_k<true><<<256, 64, 0, stream>>>(U, b3, c3, hout, hout, 512);

  // ---- logits: M=4096 N=32000 K=512, 2000 tiles, colmajor (A-locality) ----
  gemm_stream_k<<<256, 1024, 0, stream>>>(hout, embbf, (float*)d_out, obias,
                                          32000, 512, 2000, 125, 1);
}

// Round 8
// 661.658 us; speedup vs baseline: 2.0628x; 1.6208x over previous
//
#include <hip/hip_runtime.h>

// ---------------------------------------------------------------------------
// SRU LM: emb-gather -> SRU(512->1024,k4) -> 4x SRU(1024,k3) -> SRU(1024->512,k4)
//         -> logits = h @ emb^T + bias
// L=128 B=32 E=512 D=1024 V=32000 MID=4
// Round 8 = round-4 skeleton (multi-kernel; K-stream reverted — its C-write
// sat before vmcnt(4), draining 262KB of stores per tile) + two write fixes:
//  * GEMM epilogue loop order m,r outer / n inner: 4 back-to-back 64B store
//    segments complete each 128B line (round-7 counters: WRITE 984MB vs 524
//    logical, FETCH 284MB ~= C-line RMW + B — partial-line amplification).
//  * prep transposes in 64x64 tiles -> 128B-per-instruction output rows.
// GEMM: 256x256 tile, 16 waves, BK=64 dbuf, counted vmcnt, slot-XOR swizzle,
// XCD swizzle.  Scans: 4-deep pipelined.  U scratch in d_out.
// ---------------------------------------------------------------------------

typedef __attribute__((ext_vector_type(8))) __bf16 bf16x8;
typedef __attribute__((ext_vector_type(4))) float f32x4;
typedef __attribute__((ext_vector_type(4))) float float4v;
typedef __attribute__((ext_vector_type(4))) unsigned short u16x4;

__device__ __forceinline__ unsigned short f2bf(float f) {
  unsigned int u = __builtin_bit_cast(unsigned int, f);
  u += 0x7fffu + ((u >> 16) & 1u);          // RNE
  return (unsigned short)(u >> 16);
}
__device__ __forceinline__ float bf2f(unsigned short v) {
  unsigned int u = ((unsigned int)v) << 16;
  return __builtin_bit_cast(float, u);
}

#define GLDS16(SRC, DST)                                                      \
  __builtin_amdgcn_global_load_lds(                                           \
      (__attribute__((address_space(1))) void*)(SRC),                         \
      (__attribute__((address_space(3))) void*)(DST), 16, 0, 0)

// Stage one 256x64 bf16 operand tile into LDS.  1024 threads x 16B = 16 KB
// per call -> 2 calls (128 rows each).  LDS[row][slot] linear; stored slot s
// holds global 16B-slot s ^ (row&7) (pre-swizzled source, linear dest).
__device__ __forceinline__ void stage_tile(const unsigned short* __restrict__ G,
                                           unsigned short* lds_tile,
                                           int row0, size_t ldK, int k0,
                                           int w, int srow, int sslot) {
#pragma unroll
  for (int j = 0; j < 2; ++j) {
    const unsigned short* src =
        G + (size_t)(row0 + j * 128 + w * 8 + srow) * ldK + k0 + sslot * 8;
    GLDS16(src, lds_tile + j * 8192 + w * 512);
  }
}

// ---------------------------------------------------------------------------
// 256x256-tile GEMM, 16 waves.  C[m][n] = sum_k A[m][k]*B[n][k] (+bias[n]).
// A:(M,K) bf16, B:(N,K) bf16, C:(M,N) fp32.  M%256==0, N%256==0, K%64==0,
// K/64 >= 3, grid%8==0.
// ---------------------------------------------------------------------------
__global__ __launch_bounds__(1024, 4)
void gemm256(const unsigned short* __restrict__ A,
             const unsigned short* __restrict__ B,
             float* __restrict__ C, const float* __restrict__ bias,
             int M, int N, int K) {
  __shared__ __align__(16) unsigned short lds[2][2][16384];  // [buf][A/B][256*64]

  const int tid  = threadIdx.x;
  const int lane = tid & 63;
  const int w    = tid >> 6;            // 0..15
  const int wm = w >> 2, wn = w & 3;    // 4x4 wave grid, 64x64 out per wave

  // bijective XCD swizzle (grid % 8 == 0 for all our shapes)
  const int nwg  = gridDim.x;
  const int orig = blockIdx.x;
  const int wg   = (orig & 7) * (nwg >> 3) + (orig >> 3);
  const int nbx  = N >> 8;
  const int bx = wg % nbx, by = wg / nbx;
  const int m0 = by * 256, n0 = bx * 256;

  const int srow  = lane >> 3;
  const int sslot = (lane & 7) ^ srow;
  const int fr = lane & 15;
  const int lg = lane >> 4;

  f32x4 acc[4][4] = {};                 // 64 VGPR

  const int NT = K >> 6;

  // prologue: stage tiles 0 and 1 (4 loads each)
  stage_tile(A, &lds[0][0][0], m0, K, 0,  w, srow, sslot);
  stage_tile(B, &lds[0][1][0], n0, K, 0,  w, srow, sslot);
  stage_tile(A, &lds[1][0][0], m0, K, 64, w, srow, sslot);
  stage_tile(B, &lds[1][1][0], n0, K, 64, w, srow, sslot);
  asm volatile("s_waitcnt vmcnt(4)" ::: "memory");   // tile0 landed
  __builtin_amdgcn_s_barrier();

  int cur = 0;
  for (int t = 0; t < NT; ++t) {
    const unsigned short* As = &lds[cur][0][0];
    const unsigned short* Bs = &lds[cur][1][0];
    bf16x8 bfr[2][4];                   // live across the 4 phases
#pragma unroll
    for (int q = 0; q < 4; ++q) {
      if (q == 0) {
#pragma unroll
        for (int kk = 0; kk < 2; ++kk)
#pragma unroll
          for (int n = 0; n < 4; ++n) {
            const int row  = wn * 64 + n * 16 + fr;
            const int slot = (kk * 4 + lg) ^ (row & 7);
            bfr[kk][n] = *(const bf16x8*)&Bs[row * 64 + slot * 8];
          }
      }
      bf16x8 afr[2];
#pragma unroll
      for (int kk = 0; kk < 2; ++kk) {
        const int row  = wm * 64 + q * 16 + fr;
        const int slot = (kk * 4 + lg) ^ (row & 7);
        afr[kk] = *(const bf16x8*)&As[row * 64 + slot * 8];
      }
      __builtin_amdgcn_s_barrier();
      asm volatile("s_waitcnt lgkmcnt(0)" ::: "memory");
      __builtin_amdgcn_sched_barrier(0);
      __builtin_amdgcn_s_setprio(1);
#pragma unroll
      for (int kk = 0; kk < 2; ++kk)
#pragma unroll
        for (int n = 0; n < 4; ++n)
          acc[q][n] = __builtin_amdgcn_mfma_f32_16x16x32_bf16(
              afr[kk], bfr[kk][n], acc[q][n], 0, 0, 0);
      __builtin_amdgcn_s_setprio(0);
      __builtin_amdgcn_s_barrier();
    }
    // tile boundary: buf[cur] consumed -> stage tile t+2 into it, then
    // counted wait: newest 4 (tile t+2) stay in flight, tile t+1 landed.
    __builtin_amdgcn_sched_barrier(0);
    if (t + 2 < NT) {
      const int k2 = (t + 2) << 6;
      stage_tile(A, &lds[cur][0][0], m0, K, k2, w, srow, sslot);
      stage_tile(B, &lds[cur][1][0], n0, K, k2, w, srow, sslot);
      asm volatile("s_waitcnt vmcnt(4)" ::: "memory");
    } else {
      asm volatile("s_waitcnt vmcnt(0)" ::: "memory");
    }
    __builtin_amdgcn_s_barrier();
    __builtin_amdgcn_sched_barrier(0);
    cur ^= 1;
  }

  // epilogue: C write (+bias).  Loop order m,r outer / n inner: the 4 n-
  // segments (64B each) of a row are stored back-to-back, so 128B lines are
  // completed immediately (round-7 lesson: n-outer order caused ~1.9x write
  // amplification + C-line RMW fetches).
  float bv[4];
#pragma unroll
  for (int n = 0; n < 4; ++n)
    bv[n] = bias ? bias[n0 + wn * 64 + n * 16 + fr] : 0.0f;
#pragma unroll
  for (int m = 0; m < 4; ++m) {
    const int row = m0 + wm * 64 + m * 16 + lg * 4;
#pragma unroll
    for (int r = 0; r < 4; ++r) {
      float* Crow = C + (size_t)(row + r) * N + n0 + wn * 64 + fr;
#pragma unroll
      for (int n = 0; n < 4; ++n)
        Crow[n * 16] = acc[m][n][r] + bv[n];
    }
  }
}

// ---------------------------------------------------------------------------
// SRU scan, 4-deep software-pipelined.  One thread per (b,d) chain, L=128.
// ---------------------------------------------------------------------------
template <bool K4>
__global__ void scan_k(const float* __restrict__ U, const float* __restrict__ bias,
                       const float* __restrict__ c0,
                       const unsigned short* __restrict__ hin,
                       unsigned short* __restrict__ hout, int n_out) {
  const int idx = blockIdx.x * 64 + threadIdx.x;     // 0 .. 32*n_out
  const int b = idx / n_out;
  const int d = idx - b * n_out;
  const float biasf = bias[d];
  const float biasr = bias[n_out + d];
  float c = c0[idx];
  const int rowlen = (K4 ? 4 : 3) * n_out;
  const float* Up = U + (size_t)b * rowlen + d;
  const size_t lstride = (size_t)32 * rowlen;
  const unsigned short* hp = hin + (size_t)b * n_out + d;
  unsigned short* op = hout + (size_t)b * n_out + d;
  const size_t hstride = (size_t)32 * n_out;

  float xt0, fr0, rr0, hw0, xt1, fr1, rr1, hw1;
  float xt2, fr2, rr2, hw2, xt3, fr3, rr3, hw3;

#define SRU_LOAD(S)                                                           \
  do {                                                                        \
    xt##S = Up[0];                                                            \
    fr##S = Up[n_out];                                                        \
    rr##S = Up[2 * n_out];                                                    \
    hw##S = K4 ? Up[3 * n_out] : bf2f(*hp);                                   \
    Up += lstride;                                                            \
    hp += hstride;                                                            \
  } while (0)

#define SRU_STEP(S)                                                           \
  do {                                                                        \
    const float f = 1.0f / (1.0f + __expf(-(fr##S + biasf)));                 \
    const float r = 1.0f / (1.0f + __expf(-(rr##S + biasr)));                 \
    c = f * c + (1.0f - f) * xt##S;                                           \
    const float e2 = __expf(2.0f * c);                                        \
    const float g = 1.0f - 2.0f / (e2 + 1.0f);                                \
    *op = f2bf(r * g + (1.0f - r) * hw##S);                                   \
    op += hstride;                                                            \
  } while (0)

  SRU_LOAD(0); SRU_LOAD(1); SRU_LOAD(2); SRU_LOAD(3);   // l = 0..3
  for (int l = 0; l < 124; l += 4) {                    // l = 0,4,...,120
    SRU_STEP(0); SRU_LOAD(0);                           // load l+4
    SRU_STEP(1); SRU_LOAD(1);
    SRU_STEP(2); SRU_LOAD(2);
    SRU_STEP(3); SRU_LOAD(3);
  }
  SRU_STEP(0); SRU_STEP(1); SRU_STEP(2); SRU_STEP(3);   // l = 124..127
#undef SRU_LOAD
#undef SRU_STEP
}

// ---------------------------------------------------------------------------
// Fused prep: emb->bf16 cvt, token gather, all 6 weight transposes.
// Transposes in 64x64 tiles: output rows are 64 k-contig bf16 = 128B per
// store instruction (full-line writes; 32x32 tiles wrote 64B partials).
// Range dispatch on blockIdx.x; 256 threads/block.
//   [0,16000)       cvt   emb (16,384,000 f32 -> bf16), 4/thread
//   [16000,24192)   embed gather -> h0 (4096 x 512 bf16)
//   [24192,24704)   T W1  (512 x 4096)   -> W1t : 64x8   = 512 tiles
//   [24704,27776)   T W2[i] (1024x3072)  -> W2t : 48x16x4= 3072 tiles
//   [27776,28288)   T W3  (1024 x 2048)  -> W3t : 32x16  = 512 tiles
// ---------------------------------------------------------------------------
__device__ __forceinline__ void transpose_tile64(const float* __restrict__ W,
                                                 unsigned short* __restrict__ Wt,
                                                 int K, int N, int bx, int by,
                                                 int tid) {
  __shared__ float tile[64][65];
  const int n0 = bx * 64, k0 = by * 64;
  const int tx = tid & 63, ty = tid >> 6;   // (64,4)
#pragma unroll
  for (int i = 0; i < 64; i += 4)
    tile[ty + i][tx] = W[(size_t)(k0 + ty + i) * N + n0 + tx];
  __syncthreads();
#pragma unroll
  for (int i = 0; i < 64; i += 4)
    Wt[(size_t)(n0 + ty + i) * K + k0 + tx] = f2bf(tile[tx][ty + i]);
}

__global__ void prep_k(const int* __restrict__ x, const float* __restrict__ emb,
                       const float* __restrict__ W1, const float* __restrict__ W2,
                       const float* __restrict__ W3,
                       unsigned short* __restrict__ embbf,
                       unsigned short* __restrict__ h0,
                       unsigned short* __restrict__ W1t,
                       unsigned short* __restrict__ W2t,
                       unsigned short* __restrict__ W3t) {
  const int blk = blockIdx.x;
  const int tid = threadIdx.x;
  if (blk < 16000) {                                   // cvt emb -> bf16
    const int i = blk * 256 + tid;
    const float4v v = ((const float4v*)emb)[i];
    u16x4 o;
    o.x = f2bf(v.x); o.y = f2bf(v.y); o.z = f2bf(v.z); o.w = f2bf(v.w);
    ((u16x4*)embbf)[i] = o;
  } else if (blk < 24192) {                            // embed gather
    const int i = (blk - 16000) * 256 + tid;           // 0..2097151
    const int row = i >> 9, e = i & 511;
    const int tok = x[row];
    h0[i] = f2bf(emb[((size_t)tok << 9) + e]);
  } else if (blk < 24704) {                            // W1: K=512 N=4096
    const int r = blk - 24192;                         // 64 x 8
    transpose_tile64(W1, W1t, 512, 4096, r & 63, r >> 6, tid);
  } else if (blk < 27776) {                            // W2[i]: K=1024 N=3072
    const int r = blk - 24704;
    const int i = r / 768, rr = r - i * 768;           // 48 x 16 per layer
    transpose_tile64(W2 + (size_t)i * 3145728, W2t + (size_t)i * 3145728,
                     1024, 3072, rr % 48, rr / 48, tid);
  } else {                                             // W3: K=1024 N=2048
    const int r = blk - 27776;                         // 32 x 16
    transpose_tile64(W3, W3t, 1024, 2048, r & 31, r >> 5, tid);
  }
}

extern "C" void kernel_launch(void* const* d_in, const int* in_sizes, int n_in,
                              void* d_out, int out_size, void* d_ws, size_t ws_size,
                              hipStream_t stream) {
  (void)in_sizes; (void)n_in; (void)out_size; (void)ws_size;
  const int*   x     = (const int*)d_in[0];
  const float* c1    = (const float*)d_in[1];
  const float* c2    = (const float*)d_in[2];
  const float* c3    = (const float*)d_in[3];
  const float* emb   = (const float*)d_in[4];
  const float* obias = (const float*)d_in[5];
  const float* W1    = (const float*)d_in[6];
  const float* b1    = (const float*)d_in[7];
  const float* W2    = (const float*)d_in[8];
  const float* b2    = (const float*)d_in[9];
  const float* W3    = (const float*)d_in[10];
  const float* b3    = (const float*)d_in[11];

  char* ws = (char*)d_ws;
  unsigned short* hbfA  = (unsigned short*)ws;                  //  8,388,608 B
  unsigned short* hbfB  = (unsigned short*)(ws + 8388608);      //  8,388,608 B
  unsigned short* embbf = (unsigned short*)(ws + 16777216);     // 32,768,000 B
  unsigned short* W1t   = (unsigned short*)(ws + 49545216);     //  4,194,304 B
  unsigned short* W2t   = (unsigned short*)(ws + 53739520);     // 25,165,824 B
  unsigned short* W3t   = (unsigned short*)(ws + 78905344);     //  4,194,304 B
  float* U = (float*)d_out;   // up to 4096*4096 fp32 = 67 MB scratch; d_out is
                              // fully overwritten by the final logits GEMM.

  // all input prep in one launch (cvt, gather, 6 transposes — independent)
  prep_k<<<28288, 256, 0, stream>>>(x, emb, W1, W2, W3, embbf, hbfA,
                                    W1t, W2t, W3t);

  // ---- layer 1: (512 -> 1024, k=4) ----
  gemm256<<<256, 1024, 0, stream>>>(hbfA, W1t, U, nullptr, 4096, 4096, 512);
  scan_k<true><<<512, 64, 0, stream>>>(U, b1, c1, hbfB, hbfB, 1024);

  // ---- mid layers: 4x (1024 -> 1024, k=3, hw = input) ----
  const unsigned short* hin = hbfB;
  unsigned short* hout = hbfA;
  for (int i = 0; i < 4; ++i) {
    gemm256<<<192, 1024, 0, stream>>>(hin, W2t + (size_t)i * 3145728, U, nullptr,
                                      4096, 3072, 1024);
    scan_k<false><<<512, 64, 0, stream>>>(U, b2 + i * 2048, c2 + (size_t)i * 32768,
                                          hin, hout, 1024);
    const unsigned short* t = hin; hin = hout; hout = (unsigned short*)t;
  }

  // ---- final SRU: (1024 -> 512, k=4) ----
  gemm256<<<128, 1024, 0, stream>>>(hin, W3t, U, nullptr, 4096, 2048, 1024);
  scan_k<true><<<256, 64, 0, stream>>>(U, b3, c3, hout, hout, 512);

  // ---- logits: (4096 x 32000) = h5 @ emb^T + out_bias ----
  gemm256<<<2000, 1024, 0, stream>>>(hout, embbf, (float*)d_out, obias,
                                     4096, 32000, 512);
}

// Round 9
// 625.604 us; speedup vs baseline: 2.1817x; 1.0576x over previous
//
#include <hip/hip_runtime.h>

// ---------------------------------------------------------------------------
// SRU LM: emb-gather -> SRU(512->1024,k4) -> 4x SRU(1024,k3) -> SRU(1024->512,k4)
//         -> logits = h @ emb^T + bias
// L=128 B=32 E=512 D=1024 V=32000 MID=4
// Round 9: GEMM switched to the m97/m103 structure — 128x128 tile, 256 thr
// (4 waves), single-buffered 32 KiB LDS -> 3-5 blocks/CU co-resident.
// Inter-block overlap hides prologues/barrier drains/epilogue stores (the
// 1-block/CU 256^2 kernels could not); mids use all 256 CUs (768 blocks).
// XCD-bijective swizzle with m-fastest tile order: consecutive blocks on an
// XCD share the B n-panel (L2-resident).  Write-combined epilogue (round 8).
// Scans: 4-deep pipelined.  Prep fused.  U scratch in d_out.
// ---------------------------------------------------------------------------

typedef __attribute__((ext_vector_type(8))) __bf16 bf16x8;
typedef __attribute__((ext_vector_type(4))) float f32x4;
typedef __attribute__((ext_vector_type(4))) float float4v;
typedef __attribute__((ext_vector_type(4))) unsigned short u16x4;

__device__ __forceinline__ unsigned short f2bf(float f) {
  unsigned int u = __builtin_bit_cast(unsigned int, f);
  u += 0x7fffu + ((u >> 16) & 1u);          // RNE
  return (unsigned short)(u >> 16);
}
__device__ __forceinline__ float bf2f(unsigned short v) {
  unsigned int u = ((unsigned int)v) << 16;
  return __builtin_bit_cast(float, u);
}

#define GLDS16(SRC, DST)                                                      \
  __builtin_amdgcn_global_load_lds(                                           \
      (__attribute__((address_space(1))) void*)(SRC),                         \
      (__attribute__((address_space(3))) void*)(DST), 16, 0, 0)

// ---------------------------------------------------------------------------
// 128x128-tile GEMM (m97 structure).  C[m][n] = sum_k A[m][k]*B[n][k] (+bias).
// A:(M,K) bf16, B:(N,K) bf16, C:(M,N) fp32.  M%128==0, N%128==0, K%64==0,
// grid%8==0.  256 thr = 4 waves (2x2), 64x64 out/wave (4x4 frags).
// Single-buffered BK=64: {stage; syncthreads(= vmcnt0+bar); 32 MFMA/wave;
// bar} — multi-block residency (32 KiB LDS) hides the drains.
// LDS slot-swizzle: LDS[row][slot] holds global 16B-slot (slot ^ (row&7)),
// via pre-swizzled global source + linear gl_lds dest; reads XOR back.
// Tile order: by = wg % tiles_m (m-fastest) -> consecutive wg on one XCD
// share n-panel of B (L2 reuse).
// ---------------------------------------------------------------------------
__global__ __launch_bounds__(256, 4)
void gemm128(const unsigned short* __restrict__ A,
             const unsigned short* __restrict__ B,
             float* __restrict__ C, const float* __restrict__ bias,
             int M, int N, int K, int tiles_m) {
  __shared__ __align__(16) unsigned short As[128 * 64];
  __shared__ __align__(16) unsigned short Bs[128 * 64];

  const int tid  = threadIdx.x;
  const int lane = tid & 63;
  const int wave = tid >> 6;
  const int wm = wave >> 1, wn = wave & 1;

  // bijective XCD swizzle (nwg % 8 == 0 for all our grids)
  const int nwg  = gridDim.x;
  const int orig = blockIdx.x;
  const int wg   = (orig & 7) * (nwg >> 3) + (orig >> 3);
  const int by = wg % tiles_m, bx = wg / tiles_m;   // m-fastest
  const int m0 = by * 128, n0 = bx * 128;

  // staging: per call j, wave covers 8 rows; lane -> row (lane>>3),
  // LDS 16B-slot (lane&7); global slot pre-swizzled: sslot = (lane&7)^srow
  const int srow  = lane >> 3;
  const int sslot = (lane & 7) ^ srow;

  // fragment reads: row = base + (lane&15); global slot G = (lane>>4)(+4 kk)
  // LDS slot = G ^ (row&7) = (lane>>4) ^ (lane&7) ^ (kk*4)
  const int fr = lane & 15;
  const int s0 = (lane >> 4) ^ (lane & 7);
  const int lg = lane >> 4;

  f32x4 acc[4][4] = {};

  const int ksteps = K >> 6;
  for (int ks = 0; ks < ksteps; ++ks) {
    const int k0 = ks << 6;
#pragma unroll
    for (int j = 0; j < 4; ++j) {
      const int rbase = (j * 4 + wave) * 8;          // wave-uniform
      const int r = rbase + srow;
      const unsigned short* sa = A + (size_t)(m0 + r) * K + k0 + sslot * 8;
      const unsigned short* sb = B + (size_t)(n0 + r) * K + k0 + sslot * 8;
      GLDS16(sa, &As[rbase * 64]);
      GLDS16(sb, &Bs[rbase * 64]);
    }
    __syncthreads();
#pragma unroll
    for (int kk = 0; kk < 2; ++kk) {
      const int slot = s0 ^ (kk << 2);
      bf16x8 a[4], b[4];
#pragma unroll
      for (int m = 0; m < 4; ++m)
        a[m] = *(const bf16x8*)&As[(wm * 64 + m * 16 + fr) * 64 + slot * 8];
#pragma unroll
      for (int n = 0; n < 4; ++n)
        b[n] = *(const bf16x8*)&Bs[(wn * 64 + n * 16 + fr) * 64 + slot * 8];
#pragma unroll
      for (int m = 0; m < 4; ++m)
#pragma unroll
        for (int n = 0; n < 4; ++n)
          acc[m][n] = __builtin_amdgcn_mfma_f32_16x16x32_bf16(a[m], b[n],
                                                              acc[m][n], 0, 0, 0);
    }
    __syncthreads();
  }

  // epilogue: write-combined order (m,r outer / n inner: 4 back-to-back 64B
  // segments complete each row's 256B span -> full-line L2 writes)
  float bv[4];
#pragma unroll
  for (int n = 0; n < 4; ++n)
    bv[n] = bias ? bias[n0 + wn * 64 + n * 16 + fr] : 0.0f;
#pragma unroll
  for (int m = 0; m < 4; ++m) {
    const int row = m0 + wm * 64 + m * 16 + lg * 4;
#pragma unroll
    for (int r = 0; r < 4; ++r) {
      float* Crow = C + (size_t)(row + r) * N + n0 + wn * 64 + fr;
#pragma unroll
      for (int n = 0; n < 4; ++n)
        Crow[n * 16] = acc[m][n][r] + bv[n];
    }
  }
}

// ---------------------------------------------------------------------------
// SRU scan, 4-deep software-pipelined.  One thread per (b,d) chain, L=128.
// ---------------------------------------------------------------------------
template <bool K4>
__global__ void scan_k(const float* __restrict__ U, const float* __restrict__ bias,
                       const float* __restrict__ c0,
                       const unsigned short* __restrict__ hin,
                       unsigned short* __restrict__ hout, int n_out) {
  const int idx = blockIdx.x * 64 + threadIdx.x;     // 0 .. 32*n_out
  const int b = idx / n_out;
  const int d = idx - b * n_out;
  const float biasf = bias[d];
  const float biasr = bias[n_out + d];
  float c = c0[idx];
  const int rowlen = (K4 ? 4 : 3) * n_out;
  const float* Up = U + (size_t)b * rowlen + d;
  const size_t lstride = (size_t)32 * rowlen;
  const unsigned short* hp = hin + (size_t)b * n_out + d;
  unsigned short* op = hout + (size_t)b * n_out + d;
  const size_t hstride = (size_t)32 * n_out;

  float xt0, fr0, rr0, hw0, xt1, fr1, rr1, hw1;
  float xt2, fr2, rr2, hw2, xt3, fr3, rr3, hw3;

#define SRU_LOAD(S)                                                           \
  do {                                                                        \
    xt##S = Up[0];                                                            \
    fr##S = Up[n_out];                                                        \
    rr##S = Up[2 * n_out];                                                    \
    hw##S = K4 ? Up[3 * n_out] : bf2f(*hp);                                   \
    Up += lstride;                                                            \
    hp += hstride;                                                            \
  } while (0)

#define SRU_STEP(S)                                                           \
  do {                                                                        \
    const float f = 1.0f / (1.0f + __expf(-(fr##S + biasf)));                 \
    const float r = 1.0f / (1.0f + __expf(-(rr##S + biasr)));                 \
    c = f * c + (1.0f - f) * xt##S;                                           \
    const float e2 = __expf(2.0f * c);                                        \
    const float g = 1.0f - 2.0f / (e2 + 1.0f);                                \
    *op = f2bf(r * g + (1.0f - r) * hw##S);                                   \
    op += hstride;                                                            \
  } while (0)

  SRU_LOAD(0); SRU_LOAD(1); SRU_LOAD(2); SRU_LOAD(3);   // l = 0..3
  for (int l = 0; l < 124; l += 4) {                    // l = 0,4,...,120
    SRU_STEP(0); SRU_LOAD(0);                           // load l+4
    SRU_STEP(1); SRU_LOAD(1);
    SRU_STEP(2); SRU_LOAD(2);
    SRU_STEP(3); SRU_LOAD(3);
  }
  SRU_STEP(0); SRU_STEP(1); SRU_STEP(2); SRU_STEP(3);   // l = 124..127
#undef SRU_LOAD
#undef SRU_STEP
}

// ---------------------------------------------------------------------------
// Fused prep: emb->bf16 cvt, token gather, all 6 weight transposes (64x64
// tiles -> 128B-per-instruction output rows).  256 thr/block.
// ---------------------------------------------------------------------------
__device__ __forceinline__ void transpose_tile64(const float* __restrict__ W,
                                                 unsigned short* __restrict__ Wt,
                                                 int K, int N, int bx, int by,
                                                 int tid) {
  __shared__ float tile[64][65];
  const int n0 = bx * 64, k0 = by * 64;
  const int tx = tid & 63, ty = tid >> 6;   // (64,4)
#pragma unroll
  for (int i = 0; i < 64; i += 4)
    tile[ty + i][tx] = W[(size_t)(k0 + ty + i) * N + n0 + tx];
  __syncthreads();
#pragma unroll
  for (int i = 0; i < 64; i += 4)
    Wt[(size_t)(n0 + ty + i) * K + k0 + tx] = f2bf(tile[tx][ty + i]);
}

__global__ void prep_k(const int* __restrict__ x, const float* __restrict__ emb,
                       const float* __restrict__ W1, const float* __restrict__ W2,
                       const float* __restrict__ W3,
                       unsigned short* __restrict__ embbf,
                       unsigned short* __restrict__ h0,
                       unsigned short* __restrict__ W1t,
                       unsigned short* __restrict__ W2t,
                       unsigned short* __restrict__ W3t) {
  const int blk = blockIdx.x;
  const int tid = threadIdx.x;
  if (blk < 16000) {                                   // cvt emb -> bf16
    const int i = blk * 256 + tid;
    const float4v v = ((const float4v*)emb)[i];
    u16x4 o;
    o.x = f2bf(v.x); o.y = f2bf(v.y); o.z = f2bf(v.z); o.w = f2bf(v.w);
    ((u16x4*)embbf)[i] = o;
  } else if (blk < 24192) {                            // embed gather
    const int i = (blk - 16000) * 256 + tid;           // 0..2097151
    const int row = i >> 9, e = i & 511;
    const int tok = x[row];
    h0[i] = f2bf(emb[((size_t)tok << 9) + e]);
  } else if (blk < 24704) {                            // W1: K=512 N=4096
    const int r = blk - 24192;                         // 64 x 8
    transpose_tile64(W1, W1t, 512, 4096, r & 63, r >> 6, tid);
  } else if (blk < 27776) {                            // W2[i]: K=1024 N=3072
    const int r = blk - 24704;
    const int i = r / 768, rr = r - i * 768;           // 48 x 16 per layer
    transpose_tile64(W2 + (size_t)i * 3145728, W2t + (size_t)i * 3145728,
                     1024, 3072, rr % 48, rr / 48, tid);
  } else {                                             // W3: K=1024 N=2048
    const int r = blk - 27776;                         // 32 x 16
    transpose_tile64(W3, W3t, 1024, 2048, r & 31, r >> 5, tid);
  }
}

extern "C" void kernel_launch(void* const* d_in, const int* in_sizes, int n_in,
                              void* d_out, int out_size, void* d_ws, size_t ws_size,
                              hipStream_t stream) {
  (void)in_sizes; (void)n_in; (void)out_size; (void)ws_size;
  const int*   x     = (const int*)d_in[0];
  const float* c1    = (const float*)d_in[1];
  const float* c2    = (const float*)d_in[2];
  const float* c3    = (const float*)d_in[3];
  const float* emb   = (const float*)d_in[4];
  const float* obias = (const float*)d_in[5];
  const float* W1    = (const float*)d_in[6];
  const float* b1    = (const float*)d_in[7];
  const float* W2    = (const float*)d_in[8];
  const float* b2    = (const float*)d_in[9];
  const float* W3    = (const float*)d_in[10];
  const float* b3    = (const float*)d_in[11];

  char* ws = (char*)d_ws;
  unsigned short* hbfA  = (unsigned short*)ws;                  //  8,388,608 B
  unsigned short* hbfB  = (unsigned short*)(ws + 8388608);      //  8,388,608 B
  unsigned short* embbf = (unsigned short*)(ws + 16777216);     // 32,768,000 B
  unsigned short* W1t   = (unsigned short*)(ws + 49545216);     //  4,194,304 B
  unsigned short* W2t   = (unsigned short*)(ws + 53739520);     // 25,165,824 B
  unsigned short* W3t   = (unsigned short*)(ws + 78905344);     //  4,194,304 B
  float* U = (float*)d_out;   // up to 4096*4096 fp32 = 67 MB scratch; d_out is
                              // fully overwritten by the final logits GEMM.

  // all input prep in one launch (cvt, gather, 6 transposes — independent)
  prep_k<<<28288, 256, 0, stream>>>(x, emb, W1, W2, W3, embbf, hbfA,
                                    W1t, W2t, W3t);

  // ---- layer 1: (512 -> 1024, k=4): 32x32 = 1024 tiles ----
  gemm128<<<1024, 256, 0, stream>>>(hbfA, W1t, U, nullptr, 4096, 4096, 512, 32);
  scan_k<true><<<512, 64, 0, stream>>>(U, b1, c1, hbfB, hbfB, 1024);

  // ---- mid layers: 4x (1024 -> 1024, k=3): 32x24 = 768 tiles ----
  const unsigned short* hin = hbfB;
  unsigned short* hout = hbfA;
  for (int i = 0; i < 4; ++i) {
    gemm128<<<768, 256, 0, stream>>>(hin, W2t + (size_t)i * 3145728, U, nullptr,
                                     4096, 3072, 1024, 32);
    scan_k<false><<<512, 64, 0, stream>>>(U, b2 + i * 2048, c2 + (size_t)i * 32768,
                                          hin, hout, 1024);
    const unsigned short* t = hin; hin = hout; hout = (unsigned short*)t;
  }

  // ---- final SRU: (1024 -> 512, k=4): 32x16 = 512 tiles ----
  gemm128<<<512, 256, 0, stream>>>(hin, W3t, U, nullptr, 4096, 2048, 1024, 32);
  scan_k<true><<<256, 64, 0, stream>>>(U, b3, c3, hout, hout, 512);

  // ---- logits: (4096 x 32000): 32x250 = 8000 tiles ----
  gemm128<<<8000, 256, 0, stream>>>(hout, embbf, (float*)d_out, obias,
                                    4096, 32000, 512, 32);
}

// Round 10
// 615.004 us; speedup vs baseline: 2.2193x; 1.0172x over previous
//
#include <hip/hip_runtime.h>

// ---------------------------------------------------------------------------
// SRU LM: emb-gather -> SRU(512->1024,k4) -> 4x SRU(1024,k3) -> SRU(1024->512,k4)
//         -> logits = h @ emb^T + bias
// L=128 B=32 E=512 D=1024 V=32000 MID=4
// Round 10 = round 9 + bf16 U: the 6 inner GEMMs write U in bf16 (h is
// re-quantized to bf16 before every GEMM anyway, and gate inputs are damped
// by sigmoid'<=0.25); scans read bf16.  Halves the 600MB U round-trip.
// GEMM: 128x128 tile (m97 structure), 256 thr, single-buffered 32KiB LDS,
// 3-5 blocks/CU co-resident; XCD-bijective swizzle, m-fastest tile order;
// write-combined epilogue.  Scans: 4-deep pipelined.  Prep fused.
// U scratch lives in d_out (bf16, 34MB max; logits overwrite d_out at end).
// ---------------------------------------------------------------------------

typedef __attribute__((ext_vector_type(8))) __bf16 bf16x8;
typedef __attribute__((ext_vector_type(4))) float f32x4;
typedef __attribute__((ext_vector_type(4))) float float4v;
typedef __attribute__((ext_vector_type(4))) unsigned short u16x4;

__device__ __forceinline__ unsigned short f2bf(float f) {
  unsigned int u = __builtin_bit_cast(unsigned int, f);
  u += 0x7fffu + ((u >> 16) & 1u);          // RNE
  return (unsigned short)(u >> 16);
}
__device__ __forceinline__ float bf2f(unsigned short v) {
  unsigned int u = ((unsigned int)v) << 16;
  return __builtin_bit_cast(float, u);
}

#define GLDS16(SRC, DST)                                                      \
  __builtin_amdgcn_global_load_lds(                                           \
      (__attribute__((address_space(1))) void*)(SRC),                         \
      (__attribute__((address_space(3))) void*)(DST), 16, 0, 0)

// ---------------------------------------------------------------------------
// 128x128-tile GEMM (m97 structure).  C[m][n] = sum_k A[m][k]*B[n][k].
// A:(M,K) bf16, B:(N,K) bf16.  BF16OUT: C bf16 (no bias) else C fp32 (+bias).
// M%128==0, N%128==0, K%64==0, grid%8==0.  256 thr = 4 waves (2x2),
// 64x64 out/wave (4x4 frags).  Single-buffered BK=64.
// LDS slot-swizzle: LDS[row][slot] = global 16B-slot (slot ^ (row&7)).
// Tile order m-fastest: consecutive wg on an XCD share B n-panel (L2).
// ---------------------------------------------------------------------------
template <bool BF16OUT>
__global__ __launch_bounds__(256, 4)
void gemm128(const unsigned short* __restrict__ A,
             const unsigned short* __restrict__ B,
             void* __restrict__ Cv, const float* __restrict__ bias,
             int M, int N, int K, int tiles_m) {
  __shared__ __align__(16) unsigned short As[128 * 64];
  __shared__ __align__(16) unsigned short Bs[128 * 64];

  const int tid  = threadIdx.x;
  const int lane = tid & 63;
  const int wave = tid >> 6;
  const int wm = wave >> 1, wn = wave & 1;

  // bijective XCD swizzle (nwg % 8 == 0 for all our grids)
  const int nwg  = gridDim.x;
  const int orig = blockIdx.x;
  const int wg   = (orig & 7) * (nwg >> 3) + (orig >> 3);
  const int by = wg % tiles_m, bx = wg / tiles_m;   // m-fastest
  const int m0 = by * 128, n0 = bx * 128;

  const int srow  = lane >> 3;
  const int sslot = (lane & 7) ^ srow;
  const int fr = lane & 15;
  const int s0 = (lane >> 4) ^ (lane & 7);
  const int lg = lane >> 4;

  f32x4 acc[4][4] = {};

  const int ksteps = K >> 6;
  for (int ks = 0; ks < ksteps; ++ks) {
    const int k0 = ks << 6;
#pragma unroll
    for (int j = 0; j < 4; ++j) {
      const int rbase = (j * 4 + wave) * 8;          // wave-uniform
      const int r = rbase + srow;
      const unsigned short* sa = A + (size_t)(m0 + r) * K + k0 + sslot * 8;
      const unsigned short* sb = B + (size_t)(n0 + r) * K + k0 + sslot * 8;
      GLDS16(sa, &As[rbase * 64]);
      GLDS16(sb, &Bs[rbase * 64]);
    }
    __syncthreads();
#pragma unroll
    for (int kk = 0; kk < 2; ++kk) {
      const int slot = s0 ^ (kk << 2);
      bf16x8 a[4], b[4];
#pragma unroll
      for (int m = 0; m < 4; ++m)
        a[m] = *(const bf16x8*)&As[(wm * 64 + m * 16 + fr) * 64 + slot * 8];
#pragma unroll
      for (int n = 0; n < 4; ++n)
        b[n] = *(const bf16x8*)&Bs[(wn * 64 + n * 16 + fr) * 64 + slot * 8];
#pragma unroll
      for (int m = 0; m < 4; ++m)
#pragma unroll
        for (int n = 0; n < 4; ++n)
          acc[m][n] = __builtin_amdgcn_mfma_f32_16x16x32_bf16(a[m], b[n],
                                                              acc[m][n], 0, 0, 0);
    }
    __syncthreads();
  }

  // epilogue, write-combined order (m,r outer / n inner — round-8 lesson):
  // fp32: 4 x 64B segments/row back-to-back; bf16: 4 x 32B segs = 128B line.
  if constexpr (BF16OUT) {
    unsigned short* C = (unsigned short*)Cv;
#pragma unroll
    for (int m = 0; m < 4; ++m) {
      const int row = m0 + wm * 64 + m * 16 + lg * 4;
#pragma unroll
      for (int r = 0; r < 4; ++r) {
        unsigned short* Crow = C + (size_t)(row + r) * N + n0 + wn * 64 + fr;
#pragma unroll
        for (int n = 0; n < 4; ++n)
          Crow[n * 16] = f2bf(acc[m][n][r]);
      }
    }
  } else {
    float* C = (float*)Cv;
    float bv[4];
#pragma unroll
    for (int n = 0; n < 4; ++n)
      bv[n] = bias ? bias[n0 + wn * 64 + n * 16 + fr] : 0.0f;
#pragma unroll
    for (int m = 0; m < 4; ++m) {
      const int row = m0 + wm * 64 + m * 16 + lg * 4;
#pragma unroll
      for (int r = 0; r < 4; ++r) {
        float* Crow = C + (size_t)(row + r) * N + n0 + wn * 64 + fr;
#pragma unroll
        for (int n = 0; n < 4; ++n)
          Crow[n * 16] = acc[m][n][r] + bv[n];
      }
    }
  }
}

// ---------------------------------------------------------------------------
// SRU scan, 4-deep software-pipelined.  One thread per (b,d) chain, L=128.
// U is bf16 (L,B,k*n_out).  hw = U[...,3n:] if K4 else bf16 hin.
// ---------------------------------------------------------------------------
template <bool K4>
__global__ void scan_k(const unsigned short* __restrict__ U,
                       const float* __restrict__ bias,
                       const float* __restrict__ c0,
                       const unsigned short* __restrict__ hin,
                       unsigned short* __restrict__ hout, int n_out) {
  const int idx = blockIdx.x * 64 + threadIdx.x;     // 0 .. 32*n_out
  const int b = idx / n_out;
  const int d = idx - b * n_out;
  const float biasf = bias[d];
  const float biasr = bias[n_out + d];
  float c = c0[idx];
  const int rowlen = (K4 ? 4 : 3) * n_out;
  const unsigned short* Up = U + (size_t)b * rowlen + d;
  const size_t lstride = (size_t)32 * rowlen;
  const unsigned short* hp = hin + (size_t)b * n_out + d;
  unsigned short* op = hout + (size_t)b * n_out + d;
  const size_t hstride = (size_t)32 * n_out;

  float xt0, fr0, rr0, hw0, xt1, fr1, rr1, hw1;
  float xt2, fr2, rr2, hw2, xt3, fr3, rr3, hw3;

#define SRU_LOAD(S)                                                           \
  do {                                                                        \
    xt##S = bf2f(Up[0]);                                                      \
    fr##S = bf2f(Up[n_out]);                                                  \
    rr##S = bf2f(Up[2 * n_out]);                                              \
    hw##S = K4 ? bf2f(Up[3 * n_out]) : bf2f(*hp);                             \
    Up += lstride;                                                            \
    hp += hstride;                                                            \
  } while (0)

#define SRU_STEP(S)                                                           \
  do {                                                                        \
    const float f = 1.0f / (1.0f + __expf(-(fr##S + biasf)));                 \
    const float r = 1.0f / (1.0f + __expf(-(rr##S + biasr)));                 \
    c = f * c + (1.0f - f) * xt##S;                                           \
    const float e2 = __expf(2.0f * c);                                        \
    const float g = 1.0f - 2.0f / (e2 + 1.0f);                                \
    *op = f2bf(r * g + (1.0f - r) * hw##S);                                   \
    op += hstride;                                                            \
  } while (0)

  SRU_LOAD(0); SRU_LOAD(1); SRU_LOAD(2); SRU_LOAD(3);   // l = 0..3
  for (int l = 0; l < 124; l += 4) {                    // l = 0,4,...,120
    SRU_STEP(0); SRU_LOAD(0);                           // load l+4
    SRU_STEP(1); SRU_LOAD(1);
    SRU_STEP(2); SRU_LOAD(2);
    SRU_STEP(3); SRU_LOAD(3);
  }
  SRU_STEP(0); SRU_STEP(1); SRU_STEP(2); SRU_STEP(3);   // l = 124..127
#undef SRU_LOAD
#undef SRU_STEP
}

// ---------------------------------------------------------------------------
// Fused prep: emb->bf16 cvt, token gather, all 6 weight transposes (64x64
// tiles -> 128B-per-instruction output rows).  256 thr/block.
// ---------------------------------------------------------------------------
__device__ __forceinline__ void transpose_tile64(const float* __restrict__ W,
                                                 unsigned short* __restrict__ Wt,
                                                 int K, int N, int bx, int by,
                                                 int tid) {
  __shared__ float tile[64][65];
  const int n0 = bx * 64, k0 = by * 64;
  const int tx = tid & 63, ty = tid >> 6;   // (64,4)
#pragma unroll
  for (int i = 0; i < 64; i += 4)
    tile[ty + i][tx] = W[(size_t)(k0 + ty + i) * N + n0 + tx];
  __syncthreads();
#pragma unroll
  for (int i = 0; i < 64; i += 4)
    Wt[(size_t)(n0 + ty + i) * K + k0 + tx] = f2bf(tile[tx][ty + i]);
}

__global__ void prep_k(const int* __restrict__ x, const float* __restrict__ emb,
                       const float* __restrict__ W1, const float* __restrict__ W2,
                       const float* __restrict__ W3,
                       unsigned short* __restrict__ embbf,
                       unsigned short* __restrict__ h0,
                       unsigned short* __restrict__ W1t,
                       unsigned short* __restrict__ W2t,
                       unsigned short* __restrict__ W3t) {
  const int blk = blockIdx.x;
  const int tid = threadIdx.x;
  if (blk < 16000) {                                   // cvt emb -> bf16
    const int i = blk * 256 + tid;
    const float4v v = ((const float4v*)emb)[i];
    u16x4 o;
    o.x = f2bf(v.x); o.y = f2bf(v.y); o.z = f2bf(v.z); o.w = f2bf(v.w);
    ((u16x4*)embbf)[i] = o;
  } else if (blk < 24192) {                            // embed gather
    const int i = (blk - 16000) * 256 + tid;           // 0..2097151
    const int row = i >> 9, e = i & 511;
    const int tok = x[row];
    h0[i] = f2bf(emb[((size_t)tok << 9) + e]);
  } else if (blk < 24704) {                            // W1: K=512 N=4096
    const int r = blk - 24192;                         // 64 x 8
    transpose_tile64(W1, W1t, 512, 4096, r & 63, r >> 6, tid);
  } else if (blk < 27776) {                            // W2[i]: K=1024 N=3072
    const int r = blk - 24704;
    const int i = r / 768, rr = r - i * 768;           // 48 x 16 per layer
    transpose_tile64(W2 + (size_t)i * 3145728, W2t + (size_t)i * 3145728,
                     1024, 3072, rr % 48, rr / 48, tid);
  } else {                                             // W3: K=1024 N=2048
    const int r = blk - 27776;                         // 32 x 16
    transpose_tile64(W3, W3t, 1024, 2048, r & 31, r >> 5, tid);
  }
}

extern "C" void kernel_launch(void* const* d_in, const int* in_sizes, int n_in,
                              void* d_out, int out_size, void* d_ws, size_t ws_size,
                              hipStream_t stream) {
  (void)in_sizes; (void)n_in; (void)out_size; (void)ws_size;
  const int*   x     = (const int*)d_in[0];
  const float* c1    = (const float*)d_in[1];
  const float* c2    = (const float*)d_in[2];
  const float* c3    = (const float*)d_in[3];
  const float* emb   = (const float*)d_in[4];
  const float* obias = (const float*)d_in[5];
  const float* W1    = (const float*)d_in[6];
  const float* b1    = (const float*)d_in[7];
  const float* W2    = (const float*)d_in[8];
  const float* b2    = (const float*)d_in[9];
  const float* W3    = (const float*)d_in[10];
  const float* b3    = (const float*)d_in[11];

  char* ws = (char*)d_ws;
  unsigned short* hbfA  = (unsigned short*)ws;                  //  8,388,608 B
  unsigned short* hbfB  = (unsigned short*)(ws + 8388608);      //  8,388,608 B
  unsigned short* embbf = (unsigned short*)(ws + 16777216);     // 32,768,000 B
  unsigned short* W1t   = (unsigned short*)(ws + 49545216);     //  4,194,304 B
  unsigned short* W2t   = (unsigned short*)(ws + 53739520);     // 25,165,824 B
  unsigned short* W3t   = (unsigned short*)(ws + 78905344);     //  4,194,304 B
  unsigned short* U = (unsigned short*)d_out;  // bf16 U scratch (<=34MB) in
                                               // d_out; logits overwrite it.

  // all input prep in one launch (cvt, gather, 6 transposes — independent)
  prep_k<<<28288, 256, 0, stream>>>(x, emb, W1, W2, W3, embbf, hbfA,
                                    W1t, W2t, W3t);

  // ---- layer 1: (512 -> 1024, k=4): 32x32 = 1024 tiles ----
  gemm128<true><<<1024, 256, 0, stream>>>(hbfA, W1t, U, nullptr,
                                          4096, 4096, 512, 32);
  scan_k<true><<<512, 64, 0, stream>>>(U, b1, c1, hbfB, hbfB, 1024);

  // ---- mid layers: 4x (1024 -> 1024, k=3): 32x24 = 768 tiles ----
  const unsigned short* hin = hbfB;
  unsigned short* hout = hbfA;
  for (int i = 0; i < 4; ++i) {
    gemm128<true><<<768, 256, 0, stream>>>(hin, W2t + (size_t)i * 3145728, U,
                                           nullptr, 4096, 3072, 1024, 32);
    scan_k<false><<<512, 64, 0, stream>>>(U, b2 + i * 2048, c2 + (size_t)i * 32768,
                                          hin, hout, 1024);
    const unsigned short* t = hin; hin = hout; hout = (unsigned short*)t;
  }

  // ---- final SRU: (1024 -> 512, k=4): 32x16 = 512 tiles ----
  gemm128<true><<<512, 256, 0, stream>>>(hin, W3t, U, nullptr,
                                         4096, 2048, 1024, 32);
  scan_k<true><<<256, 64, 0, stream>>>(U, b3, c3, hout, hout, 512);

  // ---- logits: (4096 x 32000): 32x250 = 8000 tiles, fp32 + bias ----
  gemm128<false><<<8000, 256, 0, stream>>>(hout, embbf, (float*)d_out, obias,
                                           4096, 32000, 512, 32);
}